// Round 1
// baseline (686.686 us; speedup 1.0000x reference)
//
#include <hip/hip_runtime.h>

typedef unsigned short u16;
typedef __bf16 bf16x8 __attribute__((ext_vector_type(8)));
typedef float f32x4 __attribute__((ext_vector_type(4)));

#define S_LEN 2048
#define H_LEN 1024

__device__ __forceinline__ u16 f2b(float f) {
  unsigned u = __float_as_uint(f);
  return (u16)((u + 0x7FFFu + ((u >> 16) & 1u)) >> 16);  // RNE
}
__device__ __forceinline__ float b2f(u16 h) { return __uint_as_float(((unsigned)h) << 16); }

// async global->LDS, 16B per lane; LDS dest must be wave-uniform base + lane*16
#define GLOAD16(gp, lp)                                   \
  __builtin_amdgcn_global_load_lds(                       \
      (__attribute__((address_space(1))) void*)(gp),      \
      (__attribute__((address_space(3))) void*)(lp), 16, 0, 0)

// ---------------- prep: fp32->bf16 casts, pack weights/biases, zero rowsums ----
__global__ __launch_bounds__(256) void prep_kernel(
    const float* __restrict__ X, const float* __restrict__ Wq,
    const float* __restrict__ Wk, const float* __restrict__ Wv,
    const float* __restrict__ bq, const float* __restrict__ bk,
    const float* __restrict__ bv, const float* __restrict__ dist,
    u16* __restrict__ Xbf, u16* __restrict__ Wbf, float* __restrict__ b_all,
    u16* __restrict__ de1, float* __restrict__ lsum) {
  size_t tid = (size_t)blockIdx.x * blockDim.x + threadIdx.x;
  size_t nth = (size_t)gridDim.x * blockDim.x;
  for (size_t i = tid; i < 4194304u; i += nth) {  // X: 16.7M floats
    float4 v = ((const float4*)X)[i];
    ushort4 o; o.x = f2b(v.x); o.y = f2b(v.y); o.z = f2b(v.z); o.w = f2b(v.w);
    ((ushort4*)Xbf)[i] = o;
  }
  for (size_t i = tid; i < 786432u; i += nth) {  // Wq|Wk|Wv concat, 3x1M floats
    int which = (int)(i >> 18);
    size_t off = i & 262143u;
    const float4* src = (const float4*)(which == 0 ? Wq : (which == 1 ? Wk : Wv));
    float4 v = src[off];
    ushort4 o; o.x = f2b(v.x); o.y = f2b(v.y); o.z = f2b(v.z); o.w = f2b(v.w);
    ((ushort4*)Wbf)[i] = o;
  }
  for (size_t i = tid; i < 256u; i += nth) {  // dist_emb row 1 (only row that matters)
    float4 v = ((const float4*)(dist + H_LEN))[i];
    ushort4 o; o.x = f2b(v.x); o.y = f2b(v.y); o.z = f2b(v.z); o.w = f2b(v.w);
    ((ushort4*)de1)[i] = o;
  }
  for (size_t i = tid; i < 3072u; i += nth)
    b_all[i] = (i < 1024) ? bq[i] : (i < 2048 ? bk[i - 1024] : bv[i - 2048]);
  for (size_t i = tid; i < 16384u; i += nth) lsum[i] = 0.f;
}

// ---------------- shared NT-GEMM core (m97 structure), templated epilogue -----
struct GArgs {
  const u16* A; const u16* B;
  long long sA, sB;     // batch strides in elements
  int ldA, ldB, K;
  u16 *Qo, *Ko, *Vo; const float* b_all;                                  // EPI 0
  const int* rel; const float* d1; const float* mask; u16* P; float* lsum;// EPI 1
  const float* lin; float* outp;                                          // EPI 2
};

template <int EPI>
__global__ __launch_bounds__(256) void gemm_nt(GArgs g) {
  const int bz = blockIdx.z;
  const u16* Abase = g.A + (size_t)bz * g.sA;
  const u16* Bbase = g.B + (size_t)bz * g.sB;
  const int m0 = blockIdx.y * 128, n0 = blockIdx.x * 128;
  __shared__ u16 As[128 * 32];
  __shared__ u16 Bs[128 * 32];
  const int tid = threadIdx.x;
  const int lane = tid & 63, w = tid >> 6;
  const int wm = w >> 1, wn = w & 1;          // wave -> 64x64 quadrant
  const int l15 = lane & 15, quad = lane >> 4;

  f32x4 acc[4][4];
  const f32x4 zero = {0.f, 0.f, 0.f, 0.f};
#pragma unroll
  for (int a = 0; a < 4; ++a)
#pragma unroll
    for (int b = 0; b < 4; ++b) acc[a][b] = zero;

  // staging: 512 16B chunks per tile, 2 per thread; chunk c -> row c/4, k (c&3)*8
  const int c0 = tid, c1 = tid + 256;
  const u16* ga0 = Abase + (size_t)(m0 + (c0 >> 2)) * g.ldA + (c0 & 3) * 8;
  const u16* ga1 = Abase + (size_t)(m0 + (c1 >> 2)) * g.ldA + (c1 & 3) * 8;
  const u16* gb0 = Bbase + (size_t)(n0 + (c0 >> 2)) * g.ldB + (c0 & 3) * 8;
  const u16* gb1 = Bbase + (size_t)(n0 + (c1 >> 2)) * g.ldB + (c1 & 3) * 8;
  u16* la0 = &As[c0 * 8]; u16* la1 = &As[c1 * 8];
  u16* lb0 = &Bs[c0 * 8]; u16* lb1 = &Bs[c1 * 8];

  for (int kt = 0; kt < g.K; kt += 32) {
    __syncthreads();
    GLOAD16(ga0 + kt, la0);
    GLOAD16(ga1 + kt, la1);
    GLOAD16(gb0 + kt, lb0);
    GLOAD16(gb1 + kt, lb1);
    __syncthreads();
    bf16x8 af[4], bfb[4];
#pragma unroll
    for (int t = 0; t < 4; ++t) {
      af[t]  = *(const bf16x8*)&As[(wm * 64 + t * 16 + l15) * 32 + quad * 8];
      bfb[t] = *(const bf16x8*)&Bs[(wn * 64 + t * 16 + l15) * 32 + quad * 8];
    }
#pragma unroll
    for (int mt = 0; mt < 4; ++mt)
#pragma unroll
      for (int nt = 0; nt < 4; ++nt)
        acc[mt][nt] = __builtin_amdgcn_mfma_f32_16x16x32_bf16(af[mt], bfb[nt], acc[mt][nt], 0, 0, 0);
  }

  // C/D layout: col = lane&15, row = quad*4 + reg (verified m89/m91)
  if constexpr (EPI == 0) {  // QKV projection: add bias, split to Q/K/V, bf16 store
#pragma unroll
    for (int mt = 0; mt < 4; ++mt)
#pragma unroll
      for (int r = 0; r < 4; ++r) {
        const int i = m0 + wm * 64 + mt * 16 + quad * 4 + r;
#pragma unroll
        for (int nt = 0; nt < 4; ++nt) {
          const int n = n0 + wn * 64 + nt * 16 + l15;
          const float v = acc[mt][nt][r] + g.b_all[n];
          const int which = n >> 10, nl = n & 1023;
          u16* dst = which == 0 ? g.Qo : (which == 1 ? g.Ko : g.Vo);
          dst[(size_t)i * H_LEN + nl] = f2b(v);
        }
      }
  }
  if constexpr (EPI == 1) {  // scores: bias+mask+exp, write P (unnormalized), rowsum
    const size_t bSS = (size_t)bz * S_LEN * S_LEN;
#pragma unroll
    for (int mt = 0; mt < 4; ++mt) {
#pragma unroll
      for (int r = 0; r < 4; ++r) {
        const int i = m0 + wm * 64 + mt * 16 + quad * 4 + r;
        const float d1v = g.d1[bz * S_LEN + i];
        const size_t rowo = bSS + (size_t)i * S_LEN;
        float psum = 0.f;
#pragma unroll
        for (int nt = 0; nt < 4; ++nt) {
          const int j = n0 + wn * 64 + nt * 16 + l15;
          const int rv = g.rel[rowo + j];
          const float logit = (acc[mt][nt][r] + (rv == 1 ? d1v : 0.f)) * 0.03125f
                              + g.mask[bz * S_LEN + j];
          const float p = __expf(logit);  // no max-shift: logits bounded by ~13
          g.P[rowo + j] = f2b(p);
          psum += p;
        }
        psum += __shfl_xor(psum, 1);
        psum += __shfl_xor(psum, 2);
        psum += __shfl_xor(psum, 4);
        psum += __shfl_xor(psum, 8);
        if (l15 == 0) atomicAdd(&g.lsum[bz * S_LEN + i], psum);
      }
    }
  }
  if constexpr (EPI == 2) {  // ctx: normalize by rowsum, fp32 store
    const size_t ob = (size_t)bz * S_LEN * H_LEN;
#pragma unroll
    for (int mt = 0; mt < 4; ++mt)
#pragma unroll
      for (int r = 0; r < 4; ++r) {
        const int i = m0 + wm * 64 + mt * 16 + quad * 4 + r;
        const float inv = 1.0f / g.lin[bz * S_LEN + i];
        const size_t rowo = ob + (size_t)i * H_LEN;
#pragma unroll
        for (int nt = 0; nt < 4; ++nt) {
          const int d = n0 + wn * 64 + nt * 16 + l15;
          g.outp[rowo + d] = acc[mt][nt][r] * inv;
        }
      }
  }
}

// ---------------- d1[i] = Q[i,:] . dist_emb[1,:]  (one wave per row) ----------
__global__ __launch_bounds__(256) void compute_d1(const u16* __restrict__ Q,
                                                  const u16* __restrict__ de1,
                                                  float* __restrict__ d1) {
  const int gid = blockIdx.x * 256 + threadIdx.x;
  const int row = gid >> 6, lane = gid & 63;
  const u16* q = Q + ((size_t)row << 10);
  float s = 0.f;
#pragma unroll
  for (int it = 0; it < 2; ++it) {
    const int k0 = it * 512 + lane * 8;
    ushort4 qa = *(const ushort4*)(q + k0);
    ushort4 qb = *(const ushort4*)(q + k0 + 4);
    ushort4 da = *(const ushort4*)(de1 + k0);
    ushort4 db = *(const ushort4*)(de1 + k0 + 4);
    s += b2f(qa.x) * b2f(da.x) + b2f(qa.y) * b2f(da.y) +
         b2f(qa.z) * b2f(da.z) + b2f(qa.w) * b2f(da.w) +
         b2f(qb.x) * b2f(db.x) + b2f(qb.y) * b2f(db.y) +
         b2f(qb.z) * b2f(db.z) + b2f(qb.w) * b2f(db.w);
  }
#pragma unroll
  for (int off = 32; off > 0; off >>= 1) s += __shfl_down(s, off);
  if (lane == 0) d1[row] = s;
}

// ---------------- V[b][j][d] -> Vt[b][d][j] (64x64 LDS tiles) -----------------
__global__ __launch_bounds__(256) void transpose_v(const u16* __restrict__ V,
                                                   u16* __restrict__ Vt) {
  const int b = blockIdx.z;
  const int j0 = blockIdx.x * 64;
  const int d0 = blockIdx.y * 64;
  __shared__ u16 t[64][72];
  const int tid = threadIdx.x;
  const int tr = tid >> 4;        // 0..15
  const int tc = (tid & 15) * 4;  // 0..60
#pragma unroll
  for (int p = 0; p < 4; ++p) {
    const int jl = p * 16 + tr;
    const u16* src = V + ((size_t)b * S_LEN + (j0 + jl)) * H_LEN + d0 + tc;
    ushort4 v = *(const ushort4*)src;
    t[jl][tc + 0] = v.x; t[jl][tc + 1] = v.y; t[jl][tc + 2] = v.z; t[jl][tc + 3] = v.w;
  }
  __syncthreads();
#pragma unroll
  for (int p = 0; p < 4; ++p) {
    const int dl = p * 16 + tr;
    ushort4 v;
    v.x = t[tc + 0][dl]; v.y = t[tc + 1][dl]; v.z = t[tc + 2][dl]; v.w = t[tc + 3][dl];
    *(ushort4*)(Vt + ((size_t)b * H_LEN + (d0 + dl)) * S_LEN + j0 + tc) = v;
  }
}

extern "C" void kernel_launch(void* const* d_in, const int* in_sizes, int n_in,
                              void* d_out, int out_size, void* d_ws, size_t ws_size,
                              hipStream_t stream) {
  (void)in_sizes; (void)n_in; (void)out_size; (void)ws_size;
  const float* X    = (const float*)d_in[0];
  const float* mask = (const float*)d_in[1];  // (B,1,1,S) zeros, but honored
  const int*   rel  = (const int*)d_in[2];
  const float* Wq   = (const float*)d_in[3];
  const float* bq   = (const float*)d_in[4];
  const float* Wk   = (const float*)d_in[5];
  const float* bk   = (const float*)d_in[6];
  const float* Wv   = (const float*)d_in[7];
  const float* bv   = (const float*)d_in[8];
  const float* dist = (const float*)d_in[9];
  float* out = (float*)d_out;

  // workspace carve-up (~230 MiB total)
  char* p = (char*)d_ws;
  u16* Xbf = (u16*)p;      p += (size_t)16384 * 1024 * 2;
  u16* Wbf = (u16*)p;      p += (size_t)3072 * 1024 * 2;
  float* b_all = (float*)p; p += 3072 * 4;
  u16* de1 = (u16*)p;      p += 4096;
  u16* Qb = (u16*)p;       p += (size_t)16384 * 1024 * 2;
  u16* Kb = (u16*)p;       p += (size_t)16384 * 1024 * 2;
  u16* Vb = (u16*)p;       p += (size_t)16384 * 1024 * 2;
  u16* Vt = (u16*)p;       p += (size_t)16384 * 1024 * 2;
  float* d1 = (float*)p;   p += 16384 * 4;
  float* lsum = (float*)p; p += 16384 * 4;
  u16* P = (u16*)p;        p += (size_t)8 * 2048 * 2048 * 2;

  prep_kernel<<<1024, 256, 0, stream>>>(X, Wq, Wk, Wv, bq, bk, bv, dist,
                                        Xbf, Wbf, b_all, de1, lsum);

  // QKV: [16384x1024] @ [3072x1024]^T
  GArgs g0 = {};
  g0.A = Xbf; g0.B = Wbf; g0.sA = 0; g0.sB = 0;
  g0.ldA = 1024; g0.ldB = 1024; g0.K = 1024;
  g0.Qo = Qb; g0.Ko = Kb; g0.Vo = Vb; g0.b_all = b_all;
  gemm_nt<0><<<dim3(24, 128, 1), dim3(256, 1, 1), 0, stream>>>(g0);

  compute_d1<<<4096, 256, 0, stream>>>(Qb, de1, d1);
  transpose_v<<<dim3(32, 16, 8), dim3(256, 1, 1), 0, stream>>>(Vb, Vt);

  // scores+exp: per batch [2048x1024] @ [2048x1024]^T
  GArgs g1 = {};
  g1.A = Qb; g1.B = Kb; g1.sA = 2048LL * 1024; g1.sB = 2048LL * 1024;
  g1.ldA = 1024; g1.ldB = 1024; g1.K = 1024;
  g1.rel = rel; g1.d1 = d1; g1.mask = mask; g1.P = P; g1.lsum = lsum;
  gemm_nt<1><<<dim3(16, 16, 8), dim3(256, 1, 1), 0, stream>>>(g1);

  // ctx: per batch [2048x2048] @ [1024x2048]^T (Vt), normalize rows
  GArgs g2 = {};
  g2.A = P; g2.B = Vt; g2.sA = 2048LL * 2048; g2.sB = 1024LL * 2048;
  g2.ldA = 2048; g2.ldB = 2048; g2.K = 2048;
  g2.lin = lsum; g2.outp = out;
  gemm_nt<2><<<dim3(8, 16, 8), dim3(256, 1, 1), 0, stream>>>(g2);
}

// Round 3
// 684.112 us; speedup vs baseline: 1.0038x; 1.0038x over previous
//
#include <hip/hip_runtime.h>

typedef unsigned short u16;
typedef __bf16 bf16x8 __attribute__((ext_vector_type(8)));
typedef u16 u16x8 __attribute__((ext_vector_type(8)));
typedef float f32x4 __attribute__((ext_vector_type(4)));

#define S_LEN 2048
#define H_LEN 1024

__device__ __forceinline__ u16 f2b(float f) {
  unsigned u = __float_as_uint(f);
  return (u16)((u + 0x7FFFu + ((u >> 16) & 1u)) >> 16);  // RNE
}
__device__ __forceinline__ float b2f(u16 h) { return __uint_as_float(((unsigned)h) << 16); }

#define GLOAD16(gp, lp)                                   \
  __builtin_amdgcn_global_load_lds(                       \
      (__attribute__((address_space(1))) void*)(gp),      \
      (__attribute__((address_space(3))) void*)(lp), 16, 0, 0)

// ---------------- prep: casts, bias pack, zero accumulators -------------------
__global__ __launch_bounds__(256) void prep_kernel(
    const float* __restrict__ X, const float* __restrict__ Wq,
    const float* __restrict__ Wk, const float* __restrict__ Wv,
    const float* __restrict__ bq, const float* __restrict__ bk,
    const float* __restrict__ bv, const float* __restrict__ dist,
    u16* __restrict__ Xbf, u16* __restrict__ Wbf, float* __restrict__ b_all,
    u16* __restrict__ de1, float* __restrict__ lsum, float* __restrict__ d1) {
  size_t tid = (size_t)blockIdx.x * blockDim.x + threadIdx.x;
  size_t nth = (size_t)gridDim.x * blockDim.x;
  for (size_t i = tid; i < 4194304u; i += nth) {  // X: 16.7M floats / 4
    float4 v = ((const float4*)X)[i];
    ushort4 o; o.x = f2b(v.x); o.y = f2b(v.y); o.z = f2b(v.z); o.w = f2b(v.w);
    ((ushort4*)Xbf)[i] = o;
  }
  for (size_t i = tid; i < 786432u; i += nth) {  // Wq|Wk|Wv
    int which = (int)(i >> 18);
    size_t off = i & 262143u;
    const float4* src = (const float4*)(which == 0 ? Wq : (which == 1 ? Wk : Wv));
    float4 v = src[off];
    ushort4 o; o.x = f2b(v.x); o.y = f2b(v.y); o.z = f2b(v.z); o.w = f2b(v.w);
    ((ushort4*)Wbf)[i] = o;
  }
  for (size_t i = tid; i < 256u; i += nth) {  // dist_emb row 1
    float4 v = ((const float4*)(dist + H_LEN))[i];
    ushort4 o; o.x = f2b(v.x); o.y = f2b(v.y); o.z = f2b(v.z); o.w = f2b(v.w);
    ((ushort4*)de1)[i] = o;
  }
  for (size_t i = tid; i < 3072u; i += nth)
    b_all[i] = (i < 1024) ? bq[i] : (i < 2048 ? bk[i - 1024] : bv[i - 2048]);
  for (size_t i = tid; i < 16384u; i += nth) { lsum[i] = 0.f; d1[i] = 0.f; }
}

// ---------------- relbits: pack (rel==1) into bitmask (after QKV, reuses Xbf) -
// 8*2048*2048 int32 elements / 32 per word = 1048576 words; each iter eats 32.
__global__ __launch_bounds__(256) void relprep_kernel(const int* __restrict__ rel,
                                                      unsigned* __restrict__ bits) {
  size_t tid = (size_t)blockIdx.x * blockDim.x + threadIdx.x;
  size_t nth = (size_t)gridDim.x * blockDim.x;
  const int4* r4 = (const int4*)rel;
  for (size_t wi = tid; wi < 1048576u; wi += nth) {
    const int4* s = r4 + wi * 8;
    unsigned m = 0;
#pragma unroll
    for (int u = 0; u < 8; ++u) {
      int4 v = s[u];
      m |= (unsigned)(v.x == 1) << (u * 4 + 0);
      m |= (unsigned)(v.y == 1) << (u * 4 + 1);
      m |= (unsigned)(v.z == 1) << (u * 4 + 2);
      m |= (unsigned)(v.w == 1) << (u * 4 + 3);
    }
    bits[wi] = m;
  }
}

// ---------------- NT-GEMM core, BK=64 (two 32-halves), templated epilogue -----
struct GArgs {
  const u16* A; const u16* B;
  long long sA, sB;
  int ldA, ldB, K;
  u16 *Qo, *Ko, *Vo; const float* b_all; const u16* de1; float* d1;       // EPI 0
  const unsigned* relbits; const float* mask; u16* P; float* lsum;        // EPI 1
  const float* lin; float* outp;                                          // EPI 2
};

template <int EPI>
__global__ __launch_bounds__(256) void gemm_nt(GArgs g) {
  const int bz = blockIdx.z;
  int bx = blockIdx.x, by = blockIdx.y;
  if constexpr (EPI == 0) {  // band swizzle: 8 m-blocks x 24 n-blocks per band
    const int lin = by * 24 + bx;
    const int band = lin / (24 * 8), rem = lin % (24 * 8);
    by = band * 8 + (rem & 7);
    bx = rem >> 3;
  }
  const u16* Abase = g.A + (size_t)bz * g.sA;
  const u16* Bbase = g.B + (size_t)bz * g.sB;
  const int m0 = by * 128, n0 = bx * 128;

  __shared__ u16 smem[16384];          // 32 KB: As|Bs during loop, C-tile after
  u16* As = smem;                      // [2 halves][128][32]
  u16* Bs = smem + 8192;

  const int tid = threadIdx.x;
  const int lane = tid & 63, w = tid >> 6;
  const int wm = w >> 1, wn = w & 1;
  const int l15 = lane & 15, quad = lane >> 4;

  f32x4 acc[4][4];
  const f32x4 zero = {0.f, 0.f, 0.f, 0.f};
#pragma unroll
  for (int a = 0; a < 4; ++a)
#pragma unroll
    for (int b = 0; b < 4; ++b) acc[a][b] = zero;

  // staging: per 32-half, 512 chunks (row c>>2, k (c&3)*8); thread does c0,c1
  const int c0 = tid, c1 = tid + 256;
  const u16* ga0 = Abase + (size_t)(m0 + (c0 >> 2)) * g.ldA + (c0 & 3) * 8;
  const u16* ga1 = Abase + (size_t)(m0 + (c1 >> 2)) * g.ldA + (c1 & 3) * 8;
  const u16* gb0 = Bbase + (size_t)(n0 + (c0 >> 2)) * g.ldB + (c0 & 3) * 8;
  const u16* gb1 = Bbase + (size_t)(n0 + (c1 >> 2)) * g.ldB + (c1 & 3) * 8;
  u16* la0 = As + c0 * 8; u16* la1 = As + c1 * 8;
  u16* lb0 = Bs + c0 * 8; u16* lb1 = Bs + c1 * 8;

  for (int kt = 0; kt < g.K; kt += 64) {
    __syncthreads();
    GLOAD16(ga0 + kt, la0);      GLOAD16(ga0 + kt + 32, la0 + 4096);
    GLOAD16(ga1 + kt, la1);      GLOAD16(ga1 + kt + 32, la1 + 4096);
    GLOAD16(gb0 + kt, lb0);      GLOAD16(gb0 + kt + 32, lb0 + 4096);
    GLOAD16(gb1 + kt, lb1);      GLOAD16(gb1 + kt + 32, lb1 + 4096);
    __syncthreads();
#pragma unroll
    for (int s = 0; s < 2; ++s) {
      bf16x8 af[4], bfb[4];
#pragma unroll
      for (int t = 0; t < 4; ++t) {
        af[t]  = *(const bf16x8*)&As[s * 4096 + (wm * 64 + t * 16 + l15) * 32 + quad * 8];
        bfb[t] = *(const bf16x8*)&Bs[s * 4096 + (wn * 64 + t * 16 + l15) * 32 + quad * 8];
      }
#pragma unroll
      for (int mt = 0; mt < 4; ++mt)
#pragma unroll
        for (int nt = 0; nt < 4; ++nt)
          acc[mt][nt] = __builtin_amdgcn_mfma_f32_16x16x32_bf16(af[mt], bfb[nt], acc[mt][nt], 0, 0, 0);
    }
  }
  __syncthreads();  // done with As/Bs; smem becomes the C staging tile

  const int nbase = n0 + wn * 64;
  // C/D layout: col = lane&15, row = quad*4 + reg

  if constexpr (EPI == 0) {  // QKV: +bias, fused d1 partial, coalesced bf16 store
    const int which = n0 >> 10;             // uniform per block
    float bv4[4], dw[4];
#pragma unroll
    for (int nt = 0; nt < 4; ++nt) {
      bv4[nt] = g.b_all[nbase + nt * 16 + l15];
      dw[nt] = (which == 0) ? b2f(g.de1[nbase + nt * 16 + l15]) : 0.f;
    }
#pragma unroll
    for (int mt = 0; mt < 4; ++mt)
#pragma unroll
      for (int r = 0; r < 4; ++r) {
        const int row = wm * 64 + mt * 16 + quad * 4 + r;
        float part = 0.f;
#pragma unroll
        for (int nt = 0; nt < 4; ++nt) {
          const float v = acc[mt][nt][r] + bv4[nt];
          part += v * dw[nt];
          const int col = wn * 64 + nt * 16 + l15;
          const int chunkS = (col >> 3) ^ (row & 15);
          smem[row * 128 + chunkS * 8 + (col & 7)] = f2b(v);
        }
        if (which == 0) {
          part += __shfl_xor(part, 1);
          part += __shfl_xor(part, 2);
          part += __shfl_xor(part, 4);
          part += __shfl_xor(part, 8);
          if (l15 == 0) atomicAdd(&g.d1[m0 + row], part);
        }
      }
    __syncthreads();
    u16* dstbuf = which == 0 ? g.Qo : (which == 1 ? g.Ko : g.Vo);
    const int nl0 = n0 & 1023;
#pragma unroll
    for (int p = 0; p < 8; ++p) {
      const int flat = p * 256 + tid;
      const int row = flat >> 4, chunk = flat & 15;
      const int chunkS = chunk ^ (row & 15);
      u16x8 v = *(const u16x8*)&smem[row * 128 + chunkS * 8];
      *(u16x8*)(dstbuf + (size_t)(m0 + row) * H_LEN + nl0 + chunk * 8) = v;
    }
  }

  if constexpr (EPI == 1) {  // scores: bitmask bias + exp + rowsum, coalesced P
    float mk[4];
#pragma unroll
    for (int nt = 0; nt < 4; ++nt) mk[nt] = g.mask[bz * S_LEN + nbase + nt * 16 + l15];
    const size_t bSS = (size_t)bz * S_LEN * S_LEN;
#pragma unroll
    for (int mt = 0; mt < 4; ++mt)
#pragma unroll
      for (int r = 0; r < 4; ++r) {
        const int row = wm * 64 + mt * 16 + quad * 4 + r;
        const int gi = bz * S_LEN + m0 + row;
        const float d1v = g.d1[gi] * 0.03125f;
        const unsigned w0 = g.relbits[(size_t)gi * 64 + (nbase >> 5)];
        const unsigned w1 = g.relbits[(size_t)gi * 64 + (nbase >> 5) + 1];
        float psum = 0.f;
#pragma unroll
        for (int nt = 0; nt < 4; ++nt) {
          const unsigned word = (nt & 2) ? w1 : w0;
          const int pos = (nt * 16 + l15) & 31;
          const float bias = ((word >> pos) & 1) ? d1v : 0.f;
          const float logit = acc[mt][nt][r] * 0.03125f + bias + mk[nt];
          const float pv = __expf(logit);  // logits bounded, no max-shift
          psum += pv;
          const int col = wn * 64 + nt * 16 + l15;
          const int chunkS = (col >> 3) ^ (row & 15);
          smem[row * 128 + chunkS * 8 + (col & 7)] = f2b(pv);
        }
        psum += __shfl_xor(psum, 1);
        psum += __shfl_xor(psum, 2);
        psum += __shfl_xor(psum, 4);
        psum += __shfl_xor(psum, 8);
        if (l15 == 0) atomicAdd(&g.lsum[gi], psum);
      }
    __syncthreads();
#pragma unroll
    for (int p = 0; p < 8; ++p) {
      const int flat = p * 256 + tid;
      const int row = flat >> 4, chunk = flat & 15;
      const int chunkS = chunk ^ (row & 15);
      u16x8 v = *(const u16x8*)&smem[row * 128 + chunkS * 8];
      *(u16x8*)(g.P + bSS + (size_t)(m0 + row) * S_LEN + n0 + chunk * 8) = v;
    }
  }

  if constexpr (EPI == 2) {  // ctx: normalize, fp32 store
    const size_t ob = (size_t)bz * S_LEN * H_LEN;
#pragma unroll
    for (int mt = 0; mt < 4; ++mt)
#pragma unroll
      for (int r = 0; r < 4; ++r) {
        const int i = m0 + wm * 64 + mt * 16 + quad * 4 + r;
        const float inv = 1.0f / g.lin[bz * S_LEN + i];
        const size_t rowo = ob + (size_t)i * H_LEN;
#pragma unroll
        for (int nt = 0; nt < 4; ++nt) {
          const int d = n0 + wn * 64 + nt * 16 + l15;
          g.outp[rowo + d] = acc[mt][nt][r] * inv;
        }
      }
  }
}

// ---------------- V[b][j][d] -> Vt[b][d][j] -----------------------------------
__global__ __launch_bounds__(256) void transpose_v(const u16* __restrict__ V,
                                                   u16* __restrict__ Vt) {
  const int b = blockIdx.z;
  const int j0 = blockIdx.x * 64;
  const int d0 = blockIdx.y * 64;
  __shared__ u16 t[64][72];
  const int tid = threadIdx.x;
  const int tr = tid >> 4;
  const int tc = (tid & 15) * 4;
#pragma unroll
  for (int p = 0; p < 4; ++p) {
    const int jl = p * 16 + tr;
    const u16* src = V + ((size_t)b * S_LEN + (j0 + jl)) * H_LEN + d0 + tc;
    ushort4 v = *(const ushort4*)src;
    t[jl][tc + 0] = v.x; t[jl][tc + 1] = v.y; t[jl][tc + 2] = v.z; t[jl][tc + 3] = v.w;
  }
  __syncthreads();
#pragma unroll
  for (int p = 0; p < 4; ++p) {
    const int dl = p * 16 + tr;
    ushort4 v;
    v.x = t[tc + 0][dl]; v.y = t[tc + 1][dl]; v.z = t[tc + 2][dl]; v.w = t[tc + 3][dl];
    *(ushort4*)(Vt + ((size_t)b * H_LEN + (d0 + dl)) * S_LEN + j0 + tc) = v;
  }
}

extern "C" void kernel_launch(void* const* d_in, const int* in_sizes, int n_in,
                              void* d_out, int out_size, void* d_ws, size_t ws_size,
                              hipStream_t stream) {
  (void)in_sizes; (void)n_in; (void)out_size; (void)ws_size;
  const float* X    = (const float*)d_in[0];
  const float* mask = (const float*)d_in[1];
  const int*   rel  = (const int*)d_in[2];
  const float* Wq   = (const float*)d_in[3];
  const float* bq   = (const float*)d_in[4];
  const float* Wk   = (const float*)d_in[5];
  const float* bk   = (const float*)d_in[6];
  const float* Wv   = (const float*)d_in[7];
  const float* bv   = (const float*)d_in[8];
  const float* dist = (const float*)d_in[9];
  float* out = (float*)d_out;

  char* p = (char*)d_ws;
  u16* Xbf = (u16*)p;      p += (size_t)16384 * 1024 * 2;   // dead after QKV -> relbits
  u16* Wbf = (u16*)p;      p += (size_t)3072 * 1024 * 2;
  float* b_all = (float*)p; p += 3072 * 4;
  u16* de1 = (u16*)p;      p += 4096;
  u16* Qb = (u16*)p;       p += (size_t)16384 * 1024 * 2;
  u16* Kb = (u16*)p;       p += (size_t)16384 * 1024 * 2;
  u16* Vb = (u16*)p;       p += (size_t)16384 * 1024 * 2;
  u16* Vt = (u16*)p;       p += (size_t)16384 * 1024 * 2;
  float* d1 = (float*)p;   p += 16384 * 4;
  float* lsum = (float*)p; p += 16384 * 4;
  u16* P = (u16*)p;        p += (size_t)8 * 2048 * 2048 * 2;
  unsigned* relbits = (unsigned*)Xbf;  // 4 MB, overlays Xbf after QKV

  prep_kernel<<<1024, 256, 0, stream>>>(X, Wq, Wk, Wv, bq, bk, bv, dist,
                                        Xbf, Wbf, b_all, de1, lsum, d1);

  GArgs g0 = {};
  g0.A = Xbf; g0.B = Wbf; g0.sA = 0; g0.sB = 0;
  g0.ldA = 1024; g0.ldB = 1024; g0.K = 1024;
  g0.Qo = Qb; g0.Ko = Kb; g0.Vo = Vb; g0.b_all = b_all; g0.de1 = de1; g0.d1 = d1;
  gemm_nt<0><<<dim3(24, 128, 1), dim3(256, 1, 1), 0, stream>>>(g0);

  relprep_kernel<<<1024, 256, 0, stream>>>(rel, relbits);
  transpose_v<<<dim3(32, 16, 8), dim3(256, 1, 1), 0, stream>>>(Vb, Vt);

  GArgs g1 = {};
  g1.A = Qb; g1.B = Kb; g1.sA = 2048LL * 1024; g1.sB = 2048LL * 1024;
  g1.ldA = 1024; g1.ldB = 1024; g1.K = 1024;
  g1.relbits = relbits; g1.d1 = d1; g1.mask = mask; g1.P = P; g1.lsum = lsum;
  gemm_nt<1><<<dim3(16, 16, 8), dim3(256, 1, 1), 0, stream>>>(g1);

  GArgs g2 = {};
  g2.A = P; g2.B = Vt; g2.sA = 2048LL * 2048; g2.sB = 1024LL * 2048;
  g2.ldA = 2048; g2.ldB = 2048; g2.K = 2048;
  g2.lin = lsum; g2.outp = out;
  gemm_nt<2><<<dim3(8, 16, 8), dim3(256, 1, 1), 0, stream>>>(g2);
}

// Round 4
// 631.123 us; speedup vs baseline: 1.0880x; 1.0840x over previous
//
#include <hip/hip_runtime.h>

typedef unsigned short u16;
typedef __bf16 bf16x8 __attribute__((ext_vector_type(8)));
typedef u16 u16x8 __attribute__((ext_vector_type(8)));
typedef float f32x4 __attribute__((ext_vector_type(4)));

#define S_LEN 2048
#define H_LEN 1024

__device__ __forceinline__ u16 f2b(float f) {
  unsigned u = __float_as_uint(f);
  return (u16)((u + 0x7FFFu + ((u >> 16) & 1u)) >> 16);  // RNE
}
__device__ __forceinline__ float b2f(u16 h) { return __uint_as_float(((unsigned)h) << 16); }

#define GLOAD16(gp, lp)                                   \
  __builtin_amdgcn_global_load_lds(                       \
      (__attribute__((address_space(1))) void*)(gp),      \
      (__attribute__((address_space(3))) void*)(lp), 16, 0, 0)

// ---------------- prep: casts, bias pack, relbits pack, zero d1 ---------------
__global__ __launch_bounds__(256) void prep_kernel(
    const float* __restrict__ X, const float* __restrict__ Wq,
    const float* __restrict__ Wk, const float* __restrict__ Wv,
    const float* __restrict__ bq, const float* __restrict__ bk,
    const float* __restrict__ bv, const float* __restrict__ dist,
    const int* __restrict__ rel,
    u16* __restrict__ Xbf, u16* __restrict__ Wbf, float* __restrict__ b_all,
    u16* __restrict__ de1, unsigned* __restrict__ bits, float* __restrict__ d1) {
  size_t tid = (size_t)blockIdx.x * blockDim.x + threadIdx.x;
  size_t nth = (size_t)gridDim.x * blockDim.x;
  for (size_t i = tid; i < 4194304u; i += nth) {  // X: 16.7M floats / 4
    float4 v = ((const float4*)X)[i];
    ushort4 o; o.x = f2b(v.x); o.y = f2b(v.y); o.z = f2b(v.z); o.w = f2b(v.w);
    ((ushort4*)Xbf)[i] = o;
  }
  for (size_t i = tid; i < 786432u; i += nth) {  // Wq|Wk|Wv
    int which = (int)(i >> 18);
    size_t off = i & 262143u;
    const float4* src = (const float4*)(which == 0 ? Wq : (which == 1 ? Wk : Wv));
    float4 v = src[off];
    ushort4 o; o.x = f2b(v.x); o.y = f2b(v.y); o.z = f2b(v.z); o.w = f2b(v.w);
    ((ushort4*)Wbf)[i] = o;
  }
  // relbits: 8*2048*2048 int32 / 32 = 1048576 words, 32 elems per iter
  const int4* r4 = (const int4*)rel;
  for (size_t wi = tid; wi < 1048576u; wi += nth) {
    const int4* s = r4 + wi * 8;
    unsigned m = 0;
#pragma unroll
    for (int u = 0; u < 8; ++u) {
      int4 v = s[u];
      m |= (unsigned)(v.x == 1) << (u * 4 + 0);
      m |= (unsigned)(v.y == 1) << (u * 4 + 1);
      m |= (unsigned)(v.z == 1) << (u * 4 + 2);
      m |= (unsigned)(v.w == 1) << (u * 4 + 3);
    }
    bits[wi] = m;
  }
  for (size_t i = tid; i < 256u; i += nth) {  // dist_emb row 1
    float4 v = ((const float4*)(dist + H_LEN))[i];
    ushort4 o; o.x = f2b(v.x); o.y = f2b(v.y); o.z = f2b(v.z); o.w = f2b(v.w);
    ((ushort4*)de1)[i] = o;
  }
  for (size_t i = tid; i < 3072u; i += nth)
    b_all[i] = (i < 1024) ? bq[i] : (i < 2048 ? bk[i - 1024] : bv[i - 2048]);
  for (size_t i = tid; i < 16384u; i += nth) d1[i] = 0.f;
}

// ---------------- NT-GEMM core, BK=64 (two 32-halves), templated epilogue -----
struct GArgs {
  const u16* A; const u16* B;
  long long sA, sB;
  int ldA, ldB, K;
  u16 *Qo, *Ko, *Vo; const float* b_all; const u16* de1; float* d1;       // EPI 0
  const unsigned* relbits; const float* mask; u16* P;                     // EPI 1
  float* outp;                                                            // EPI 2
};

template <int EPI>
__global__ __launch_bounds__(256) void gemm_nt(GArgs g) {
  const int bz = blockIdx.z;
  int bx = blockIdx.x, by = blockIdx.y;
  if constexpr (EPI == 0) {  // band swizzle: 8 m-blocks x 24 n-blocks per band
    const int lin = by * 24 + bx;
    const int band = lin / (24 * 8), rem = lin % (24 * 8);
    by = band * 8 + (rem & 7);
    bx = rem >> 3;
  }
  const u16* Abase = g.A + (size_t)bz * g.sA;
  const u16* Bbase = g.B + (size_t)bz * g.sB;
  const int m0 = by * 128, n0 = bx * 128;

  __shared__ u16 smem[16384];          // 32 KB: As|Bs during loop, C-tile after
  u16* As = smem;                      // [2 halves][128][32]
  u16* Bs = smem + 8192;

  const int tid = threadIdx.x;
  const int lane = tid & 63, w = tid >> 6;
  const int wm = w >> 1, wn = w & 1;
  const int l15 = lane & 15, quad = lane >> 4;

  f32x4 acc[4][4];
  f32x4 acc_sum[4];                    // EPI 2 only: row-sums of A (P) via ones-MFMA
  const f32x4 zero = {0.f, 0.f, 0.f, 0.f};
#pragma unroll
  for (int a = 0; a < 4; ++a) {
    acc_sum[a] = zero;
#pragma unroll
    for (int b = 0; b < 4; ++b) acc[a][b] = zero;
  }
  bf16x8 ones;
#pragma unroll
  for (int i = 0; i < 8; ++i) ones[i] = (__bf16)1.0f;

  // staging: per 32-half, 512 chunks (row c>>2, k (c&3)*8); thread does c0,c1
  const int c0 = tid, c1 = tid + 256;
  const u16* ga0 = Abase + (size_t)(m0 + (c0 >> 2)) * g.ldA + (c0 & 3) * 8;
  const u16* ga1 = Abase + (size_t)(m0 + (c1 >> 2)) * g.ldA + (c1 & 3) * 8;
  const u16* gb0 = Bbase + (size_t)(n0 + (c0 >> 2)) * g.ldB + (c0 & 3) * 8;
  const u16* gb1 = Bbase + (size_t)(n0 + (c1 >> 2)) * g.ldB + (c1 & 3) * 8;
  u16* la0 = As + c0 * 8; u16* la1 = As + c1 * 8;
  u16* lb0 = Bs + c0 * 8; u16* lb1 = Bs + c1 * 8;

  for (int kt = 0; kt < g.K; kt += 64) {
    __syncthreads();
    GLOAD16(ga0 + kt, la0);      GLOAD16(ga0 + kt + 32, la0 + 4096);
    GLOAD16(ga1 + kt, la1);      GLOAD16(ga1 + kt + 32, la1 + 4096);
    GLOAD16(gb0 + kt, lb0);      GLOAD16(gb0 + kt + 32, lb0 + 4096);
    GLOAD16(gb1 + kt, lb1);      GLOAD16(gb1 + kt + 32, lb1 + 4096);
    __syncthreads();
#pragma unroll
    for (int s = 0; s < 2; ++s) {
      bf16x8 af[4], bfb[4];
#pragma unroll
      for (int t = 0; t < 4; ++t) {
        af[t]  = *(const bf16x8*)&As[s * 4096 + (wm * 64 + t * 16 + l15) * 32 + quad * 8];
        bfb[t] = *(const bf16x8*)&Bs[s * 4096 + (wn * 64 + t * 16 + l15) * 32 + quad * 8];
      }
#pragma unroll
      for (int mt = 0; mt < 4; ++mt) {
#pragma unroll
        for (int nt = 0; nt < 4; ++nt)
          acc[mt][nt] = __builtin_amdgcn_mfma_f32_16x16x32_bf16(af[mt], bfb[nt], acc[mt][nt], 0, 0, 0);
        if constexpr (EPI == 2)  // P row-sums for softmax denominator (exact)
          acc_sum[mt] = __builtin_amdgcn_mfma_f32_16x16x32_bf16(af[mt], ones, acc_sum[mt], 0, 0, 0);
      }
    }
  }
  __syncthreads();  // done with As/Bs; smem becomes the C staging tile

  const int nbase = n0 + wn * 64;
  // C/D layout: col = lane&15, row = quad*4 + reg

  if constexpr (EPI == 0) {  // QKV: +bias, fused d1 partial, coalesced bf16 store
    const int which = n0 >> 10;             // uniform per block
    float bv4[4], dw[4];
#pragma unroll
    for (int nt = 0; nt < 4; ++nt) {
      bv4[nt] = g.b_all[nbase + nt * 16 + l15];
      dw[nt] = (which == 0) ? b2f(g.de1[nbase + nt * 16 + l15]) : 0.f;
    }
#pragma unroll
    for (int mt = 0; mt < 4; ++mt)
#pragma unroll
      for (int r = 0; r < 4; ++r) {
        const int row = wm * 64 + mt * 16 + quad * 4 + r;
        float part = 0.f;
#pragma unroll
        for (int nt = 0; nt < 4; ++nt) {
          const float v = acc[mt][nt][r] + bv4[nt];
          part += v * dw[nt];
          const int col = wn * 64 + nt * 16 + l15;
          const int chunkS = (col >> 3) ^ (row & 15);
          smem[row * 128 + chunkS * 8 + (col & 7)] = f2b(v);
        }
        if (which == 0) {
          part += __shfl_xor(part, 1);
          part += __shfl_xor(part, 2);
          part += __shfl_xor(part, 4);
          part += __shfl_xor(part, 8);
          if (l15 == 0) atomicAdd(&g.d1[m0 + row], part);
        }
      }
    __syncthreads();
    u16* dstbuf = which == 0 ? g.Qo : (which == 1 ? g.Ko : g.Vo);
    const int nl0 = n0 & 1023;
#pragma unroll
    for (int p = 0; p < 8; ++p) {
      const int flat = p * 256 + tid;
      const int row = flat >> 4, chunk = flat & 15;
      const int chunkS = chunk ^ (row & 15);
      u16x8 v = *(const u16x8*)&smem[row * 128 + chunkS * 8];
      *(u16x8*)(dstbuf + (size_t)(m0 + row) * H_LEN + nl0 + chunk * 8) = v;
    }
  }

  if constexpr (EPI == 1) {  // scores: bitmask bias + exp, coalesced P store
    float mk[4];
#pragma unroll
    for (int nt = 0; nt < 4; ++nt) mk[nt] = g.mask[bz * S_LEN + nbase + nt * 16 + l15];
    const size_t bSS = (size_t)bz * S_LEN * S_LEN;
#pragma unroll
    for (int mt = 0; mt < 4; ++mt)
#pragma unroll
      for (int r = 0; r < 4; ++r) {
        const int row = wm * 64 + mt * 16 + quad * 4 + r;
        const int gi = bz * S_LEN + m0 + row;
        const float d1v = g.d1[gi] * 0.03125f;
        const unsigned w0 = g.relbits[(size_t)gi * 64 + (nbase >> 5)];
        const unsigned w1 = g.relbits[(size_t)gi * 64 + (nbase >> 5) + 1];
#pragma unroll
        for (int nt = 0; nt < 4; ++nt) {
          const unsigned word = (nt & 2) ? w1 : w0;
          const int pos = (nt * 16 + l15) & 31;
          const float bias = ((word >> pos) & 1) ? d1v : 0.f;
          const float logit = acc[mt][nt][r] * 0.03125f + bias + mk[nt];
          const float pv = __expf(logit);  // logits bounded, no max-shift
          const int col = wn * 64 + nt * 16 + l15;
          const int chunkS = (col >> 3) ^ (row & 15);
          smem[row * 128 + chunkS * 8 + (col & 7)] = f2b(pv);
        }
      }
    __syncthreads();
#pragma unroll
    for (int p = 0; p < 8; ++p) {
      const int flat = p * 256 + tid;
      const int row = flat >> 4, chunk = flat & 15;
      const int chunkS = chunk ^ (row & 15);
      u16x8 v = *(const u16x8*)&smem[row * 128 + chunkS * 8];
      *(u16x8*)(g.P + bSS + (size_t)(m0 + row) * S_LEN + n0 + chunk * 8) = v;
    }
  }

  if constexpr (EPI == 2) {  // ctx: normalize by ones-MFMA row-sum, fp32 store
    const size_t ob = (size_t)bz * S_LEN * H_LEN;
#pragma unroll
    for (int mt = 0; mt < 4; ++mt)
#pragma unroll
      for (int r = 0; r < 4; ++r) {
        const int i = m0 + wm * 64 + mt * 16 + quad * 4 + r;
        const float inv = 1.0f / acc_sum[mt][r];
        const size_t rowo = ob + (size_t)i * H_LEN;
#pragma unroll
        for (int nt = 0; nt < 4; ++nt) {
          const int d = n0 + wn * 64 + nt * 16 + l15;
          g.outp[rowo + d] = acc[mt][nt][r] * inv;
        }
      }
  }
}

// ---------------- V[b][j][d] -> Vt[b][d][j] -----------------------------------
__global__ __launch_bounds__(256) void transpose_v(const u16* __restrict__ V,
                                                   u16* __restrict__ Vt) {
  const int b = blockIdx.z;
  const int j0 = blockIdx.x * 64;
  const int d0 = blockIdx.y * 64;
  __shared__ u16 t[64][72];
  const int tid = threadIdx.x;
  const int tr = tid >> 4;
  const int tc = (tid & 15) * 4;
#pragma unroll
  for (int p = 0; p < 4; ++p) {
    const int jl = p * 16 + tr;
    const u16* src = V + ((size_t)b * S_LEN + (j0 + jl)) * H_LEN + d0 + tc;
    ushort4 v = *(const ushort4*)src;
    t[jl][tc + 0] = v.x; t[jl][tc + 1] = v.y; t[jl][tc + 2] = v.z; t[jl][tc + 3] = v.w;
  }
  __syncthreads();
#pragma unroll
  for (int p = 0; p < 4; ++p) {
    const int dl = p * 16 + tr;
    ushort4 v;
    v.x = t[tc + 0][dl]; v.y = t[tc + 1][dl]; v.z = t[tc + 2][dl]; v.w = t[tc + 3][dl];
    *(ushort4*)(Vt + ((size_t)b * H_LEN + (d0 + dl)) * S_LEN + j0 + tc) = v;
  }
}

extern "C" void kernel_launch(void* const* d_in, const int* in_sizes, int n_in,
                              void* d_out, int out_size, void* d_ws, size_t ws_size,
                              hipStream_t stream) {
  (void)in_sizes; (void)n_in; (void)out_size; (void)ws_size;
  const float* X    = (const float*)d_in[0];
  const float* mask = (const float*)d_in[1];
  const int*   rel  = (const int*)d_in[2];
  const float* Wq   = (const float*)d_in[3];
  const float* bq   = (const float*)d_in[4];
  const float* Wk   = (const float*)d_in[5];
  const float* bk   = (const float*)d_in[6];
  const float* Wv   = (const float*)d_in[7];
  const float* bv   = (const float*)d_in[8];
  const float* dist = (const float*)d_in[9];
  float* out = (float*)d_out;

  char* p = (char*)d_ws;
  u16* Xbf = (u16*)p;      p += (size_t)16384 * 1024 * 2;
  u16* Wbf = (u16*)p;      p += (size_t)3072 * 1024 * 2;
  float* b_all = (float*)p; p += 3072 * 4;
  u16* de1 = (u16*)p;      p += 4096;
  u16* Qb = (u16*)p;       p += (size_t)16384 * 1024 * 2;
  u16* Kb = (u16*)p;       p += (size_t)16384 * 1024 * 2;
  u16* Vb = (u16*)p;       p += (size_t)16384 * 1024 * 2;
  u16* Vt = (u16*)p;       p += (size_t)16384 * 1024 * 2;
  float* d1 = (float*)p;   p += 16384 * 4;
  unsigned* relbits = (unsigned*)p; p += (size_t)1048576 * 4;
  u16* P = (u16*)p;        p += (size_t)8 * 2048 * 2048 * 2;

  prep_kernel<<<1024, 256, 0, stream>>>(X, Wq, Wk, Wv, bq, bk, bv, dist, rel,
                                        Xbf, Wbf, b_all, de1, relbits, d1);

  GArgs g0 = {};
  g0.A = Xbf; g0.B = Wbf; g0.sA = 0; g0.sB = 0;
  g0.ldA = 1024; g0.ldB = 1024; g0.K = 1024;
  g0.Qo = Qb; g0.Ko = Kb; g0.Vo = Vb; g0.b_all = b_all; g0.de1 = de1; g0.d1 = d1;
  gemm_nt<0><<<dim3(24, 128, 1), dim3(256, 1, 1), 0, stream>>>(g0);

  transpose_v<<<dim3(32, 16, 8), dim3(256, 1, 1), 0, stream>>>(Vb, Vt);

  GArgs g1 = {};
  g1.A = Qb; g1.B = Kb; g1.sA = 2048LL * 1024; g1.sB = 2048LL * 1024;
  g1.ldA = 1024; g1.ldB = 1024; g1.K = 1024;
  g1.relbits = relbits; g1.d1 = d1; g1.mask = mask; g1.P = P;
  gemm_nt<1><<<dim3(16, 16, 8), dim3(256, 1, 1), 0, stream>>>(g1);

  GArgs g2 = {};
  g2.A = P; g2.B = Vt; g2.sA = 2048LL * 2048; g2.sB = 1024LL * 2048;
  g2.ldA = 2048; g2.ldB = 2048; g2.K = 2048;
  g2.outp = out;
  gemm_nt<2><<<dim3(8, 16, 8), dim3(256, 1, 1), 0, stream>>>(g2);
}